// Round 6
// baseline (6200.440 us; speedup 1.0000x reference)
//
#include <hip/hip_runtime.h>
#include <hip/hip_fp16.h>

#define DEVINL __device__ __forceinline__

constexpr int B = 256, S = 512;
constexpr int H0 = 64, H1 = 128, H2 = 256;

typedef _Float16 f16x8 __attribute__((ext_vector_type(8)));
typedef float f32x4 __attribute__((ext_vector_type(4)));
typedef _Float16 h2v __attribute__((ext_vector_type(2)));

DEVINL float fexp2(float x) { return __builtin_amdgcn_exp2f(x); }
DEVINL float frcp(float x) { return __builtin_amdgcn_rcpf(x); }
DEVINL float fsig(float x) { return frcp(1.f + fexp2(-1.44269504088896f * x)); }
DEVINL float ftanh_(float x) { return 1.f - 2.f * frcp(1.f + fexp2(2.88539008177793f * x)); }
DEVINL h2v as_h2(unsigned u) { union { unsigned u; h2v h; } x; x.u = u; return x.h; }
DEVINL float fdot2(unsigned a, unsigned b, float c) {
  return __builtin_amdgcn_fdot2(as_h2(a), as_h2(b), c, false);
}
union FU { uint4 u; f16x8 h; };
DEVINL f16x8 as_f16x8(uint4 u) { FU x; x.u = u; return x.h; }

// LDS-only workgroup barrier: no vmcnt drain, global ops stay in flight.
DEVINL void wg_barrier() {
  asm volatile("s_waitcnt lgkmcnt(0)" ::: "memory");
  __builtin_amdgcn_s_barrier();
  asm volatile("" ::: "memory");
}

// Row permutation: r' = mt*16 + quad*4 + reg -> channel = r'>>2, gate = r'&3.
// orig torch row = gate*Hch + channel. One C-frag lane holds one channel's
// (i,f,g,o) quad (C: col=lane&15, row=(lane>>4)*4+reg).

__global__ __launch_bounds__(256) void pack_frag(const float* __restrict__ w,
    uint4* __restrict__ wp, int Hch, int Kdim, int MT, int KT) {
  int o = blockIdx.x * 256 + threadIdx.x;
  if (o >= MT * KT * 64) return;
  int lane = o & 63, fk = o >> 6;
  int kt = fk % KT, mt = fk / KT;
  int rp = mt * 16 + (lane & 15);
  int orig = (rp & 3) * Hch + (rp >> 2);
  int k0 = kt * 32 + (lane >> 4) * 8;
  unsigned r[4];
#pragma unroll
  for (int p = 0; p < 4; ++p) {
    unsigned lo = __half_as_ushort(__float2half_rn(w[(size_t)orig * Kdim + k0 + 2 * p]));
    unsigned hi = __half_as_ushort(__float2half_rn(w[(size_t)orig * Kdim + k0 + 2 * p + 1]));
    r[p] = lo | (hi << 16);
  }
  uint4 v; v.x = r[0]; v.y = r[1]; v.z = r[2]; v.w = r[3];
  wp[o] = v;
}

__global__ __launch_bounds__(256) void pack_bias(const float* __restrict__ bih,
    const float* __restrict__ bhh, float* __restrict__ bs, int Hch) {
  int rp = blockIdx.x * 256 + threadIdx.x;
  if (rp >= 4 * Hch) return;
  int orig = (rp & 3) * Hch + (rp >> 2);
  bs[rp] = bih[orig] + bhh[orig];
}

__global__ void pack_wl(const float* __restrict__ wl, unsigned* __restrict__ wlp, int n) {
  int i = threadIdx.x;
  if (i < n) {
    unsigned lo = __half_as_ushort(__float2half_rn(wl[2 * i]));
    unsigned hi = __half_as_ushort(__float2half_rn(wl[2 * i + 1]));
    wlp[i] = lo | (hi << 16);
  }
}

__global__ __launch_bounds__(256) void f2h(const float* __restrict__ x,
                                           __half* __restrict__ y, int n8) {
  int i = blockIdx.x * 256 + threadIdx.x;
  if (i >= n8) return;
  float4 a = *(const float4*)(x + i * 8);
  float4 b = *(const float4*)(x + i * 8 + 4);
  __half h[8];
  h[0] = __float2half_rn(a.x); h[1] = __float2half_rn(a.y);
  h[2] = __float2half_rn(a.z); h[3] = __float2half_rn(a.w);
  h[4] = __float2half_rn(b.x); h[5] = __float2half_rn(b.y);
  h[6] = __float2half_rn(b.z); h[7] = __float2half_rn(b.w);
  *(uint4*)(y + i * 8) = *(const uint4*)h;
}

// MFMA input GEMM -> preT in C-frag layout.
template <int KT>
__global__ __launch_bounds__(256) void ingemm_mfma(const __half* __restrict__ x,
    const uint4* __restrict__ wp, const float* __restrict__ bs,
    f32x4* __restrict__ preT, int MT, int Sc, int t0) {
  constexpr int K = KT * 32;
  const int tid = threadIdx.x, w = tid >> 6, lane = tid & 63;
  const int n16 = lane & 15, quad = lane >> 4;
  const int bt = blockIdx.x, b0 = bt * 16;
  const int tlb = blockIdx.y * 8;
  const int mb = blockIdx.z * 16;

  uint4 areg[4][KT];
#pragma unroll
  for (int im = 0; im < 4; ++im)
#pragma unroll
    for (int kt = 0; kt < KT; ++kt)
      areg[im][kt] = wp[((size_t)(mb + w * 4 + im) * KT + kt) * 64 + lane];
  f32x4 bini[4];
#pragma unroll
  for (int im = 0; im < 4; ++im)
    bini[im] = *(const f32x4*)(bs + (mb + w * 4 + im) * 16 + quad * 4);

  for (int tt = 0; tt < 8; ++tt) {
    int t = t0 + tlb + tt;
    const __half* xr = x + ((size_t)(b0 + n16) * S + t) * K + quad * 8;
    uint4 bfr[KT];
#pragma unroll
    for (int kt = 0; kt < KT; ++kt) bfr[kt] = *(const uint4*)(xr + kt * 32);
    f32x4 acc[4];
#pragma unroll
    for (int im = 0; im < 4; ++im) acc[im] = bini[im];
#pragma unroll
    for (int kt = 0; kt < KT; ++kt)
#pragma unroll
      for (int im = 0; im < 4; ++im)
        acc[im] = __builtin_amdgcn_mfma_f32_16x16x32_f16(as_f16x8(areg[im][kt]),
                                                         as_f16x8(bfr[kt]), acc[im], 0, 0, 0);
#pragma unroll
    for (int im = 0; im < 4; ++im)
      preT[((size_t)(bt * Sc + tlb + tt) * MT + mb + w * 4 + im) * 64 + lane] = acc[im];
  }
}

// Single-WG weight-stationary scan (layers 0/1). 16 WGs x 16 batch, 512 thr.
// amdgpu_waves_per_eu(2,2) pins occupancy -> allocator keeps areg resident.
template <int H>
__global__ __launch_bounds__(512) __attribute__((amdgpu_waves_per_eu(2, 2)))
void scan_s1(const uint4* __restrict__ wp, const f32x4* __restrict__ preT,
             __half* __restrict__ xout, float* __restrict__ sth,
             float* __restrict__ stc, int Sc, int t0, int first) {
  constexpr int MT = H / 4;
  constexpr int MTW = MT / 8;
  constexpr int KT = H / 32;
  constexpr int HP = H + 8;
  __shared__ __half hbo[2][16 * HP];
  const int tid = threadIdx.x, w = tid >> 6, lane = tid & 63;
  const int n16 = lane & 15, quad = lane >> 4;
  const int bt = blockIdx.x, b0 = bt * 16;

  uint4 areg[MTW][KT];
#pragma unroll
  for (int im = 0; im < MTW; ++im)
#pragma unroll
    for (int kt = 0; kt < KT; ++kt)
      areg[im][kt] = wp[((size_t)(w * MTW + im) * KT + kt) * 64 + lane];

  float cst[MTW];
#pragma unroll
  for (int im = 0; im < MTW; ++im) {
    int ch = (w * MTW + im) * 4 + quad;
    cst[im] = first ? 0.f : stc[(size_t)(b0 + n16) * H + ch];
  }
  {
    int pi = (t0 - 1) & 1;
    for (int i = tid; i < 16 * H; i += 512) {
      int n = i / H, c = i % H;
      hbo[pi][n * HP + c] = first ? __float2half_rn(0.f)
                                  : __float2half_rn(sth[(size_t)(b0 + n) * H + c]);
    }
  }
  __syncthreads();

  f32x4 nxt[MTW];
#pragma unroll
  for (int im = 0; im < MTW; ++im)
    nxt[im] = preT[((size_t)(bt * Sc) * MT + w * MTW + im) * 64 + lane];

  for (int tl = 0; tl < Sc; ++tl) {
    const int s = t0 + tl;
    const int pw = s & 1, pbl = pw ^ 1;
    f32x4 acc[MTW];
#pragma unroll
    for (int im = 0; im < MTW; ++im) acc[im] = nxt[im];
    if (tl + 1 < Sc) {
#pragma unroll
      for (int im = 0; im < MTW; ++im)
        nxt[im] = preT[((size_t)(bt * Sc + tl + 1) * MT + w * MTW + im) * 64 + lane];
    }

#pragma unroll
    for (int kt = 0; kt < KT; ++kt) {
      uint4 bf = *(const uint4*)&hbo[pbl][n16 * HP + kt * 32 + quad * 8];
#pragma unroll
      for (int im = 0; im < MTW; ++im)
        acc[im] = __builtin_amdgcn_mfma_f32_16x16x32_f16(as_f16x8(areg[im][kt]),
                                                         as_f16x8(bf), acc[im], 0, 0, 0);
    }

    if (tl > 0 && tid < 16 * (H / 8)) {  // export h(s-1)
      int n = tid / (H / 8), kq = tid % (H / 8);
      uint4 v = *(const uint4*)&hbo[pbl][n * HP + kq * 8];
      *(uint4*)(xout + ((size_t)(b0 + n) * S + (s - 1)) * H + kq * 8) = v;
    }

#pragma unroll
    for (int im = 0; im < MTW; ++im) {
      float gi = fsig(acc[im][0]);
      float gf = fsig(acc[im][1]);
      float gg = ftanh_(acc[im][2]);
      float go = fsig(acc[im][3]);
      float cn = gf * cst[im] + gi * gg;
      cst[im] = cn;
      hbo[pw][n16 * HP + (w * MTW + im) * 4 + quad] = __float2half_rn(go * ftanh_(cn));
    }
    wg_barrier();
  }

  {
    const int sl = t0 + Sc - 1, pl = sl & 1;
    if (tid < 16 * (H / 8)) {
      int n = tid / (H / 8), kq = tid % (H / 8);
      uint4 v = *(const uint4*)&hbo[pl][n * HP + kq * 8];
      *(uint4*)(xout + ((size_t)(b0 + n) * S + sl) * H + kq * 8) = v;
    }
    for (int i = tid; i < 16 * H; i += 512) {
      int n = i / H, c = i % H;
      sth[(size_t)(b0 + n) * H + c] = __half2float(hbo[pl][n * HP + c]);
    }
#pragma unroll
    for (int im = 0; im < MTW; ++im) {
      int ch = (w * MTW + im) * 4 + quad;
      stc[(size_t)(b0 + n16) * H + ch] = cst[im];
    }
  }
}

// Layer-2 scan: 32 WGs (16 batch-group pairs) x 1024 thr (16 waves, 4/SIMD).
// Each WG owns half the m-dim; weights = 64 regs/thread, pinned resident via
// amdgpu_waves_per_eu(4,4). Wave 0 alone runs the cross-WG h exchange:
// export(relaxed sc1 stores + release flag) -> own-MFMA overlap -> relaxed
// poll -> one acquire -> sc1 import into LDS. Two LDS-only barriers/step.
// Final linear fused (wave 1). Parity ping-pong on xh; one dispatch per chunk.
__global__ __launch_bounds__(1024) __attribute__((amdgpu_waves_per_eu(4, 4)))
void scan2_pair(const uint4* __restrict__ wp, const f32x4* __restrict__ preT,
                float* __restrict__ out, const unsigned* __restrict__ wlp,
                const float* __restrict__ blp, float* __restrict__ sth,
                float* __restrict__ stc, unsigned* __restrict__ xh,
                int* __restrict__ flags, int Sc, int t0, int first) {
  constexpr int HP2 = 264;  // padded row in halves (256+8)
  __shared__ __half hb[2][16 * HP2];
  __shared__ unsigned wls[128];

  const int tid = threadIdx.x, w = tid >> 6, lane = tid & 63;
  const int n16 = lane & 15, quad = lane >> 4;
  const int bt = blockIdx.x & 15, half = blockIdx.x >> 4;
  const int phalf = 1 - half;
  const int b0 = bt * 16;
  const int gm0 = half * 32 + w * 2;  // this wave's 2 m-tiles (of 64)
  const int flo = bt * 2 + half, fle = bt * 2 + phalf;

  uint4 areg[2][8];
#pragma unroll
  for (int im = 0; im < 2; ++im)
#pragma unroll
    for (int kt = 0; kt < 8; ++kt)
      areg[im][kt] = wp[((size_t)(gm0 + im) * 8 + kt) * 64 + lane];

  for (int i = tid; i < 128; i += 1024) wls[i] = wlp[i];

  float cst[2];
#pragma unroll
  for (int im = 0; im < 2; ++im) {
    int ch = (gm0 + im) * 4 + quad;
    cst[im] = first ? 0.f : stc[(size_t)(b0 + n16) * 256 + ch];
  }
  {
    int pi = (t0 - 1) & 1;
    for (int i = tid; i < 16 * 256; i += 1024) {
      int n = i >> 8, c = i & 255;
      hb[pi][n * HP2 + c] = first ? __float2half_rn(0.f)
                                  : __float2half_rn(sth[(size_t)(b0 + n) * 256 + c]);
    }
  }
  __syncthreads();

  const float bl0 = blp[0];

  f32x4 nxt[2];
#pragma unroll
  for (int im = 0; im < 2; ++im)
    nxt[im] = preT[((size_t)(bt * Sc) * 64 + gm0 + im) * 64 + lane];

  for (int tl = 0; tl < Sc; ++tl) {
    const int s = t0 + tl;
    const int pw = s & 1, pbl = pw ^ 1;
    f32x4 acc[2];
    acc[0] = nxt[0]; acc[1] = nxt[1];
    if (tl + 1 < Sc) {
#pragma unroll
      for (int im = 0; im < 2; ++im)
        nxt[im] = preT[((size_t)(bt * Sc + tl + 1) * 64 + gm0 + im) * 64 + lane];
    }

    // ---- phase 1: wave0 export h(s-1); all waves own-half MFMA; wave0 import
    if (w == 0 && tl > 0) {
      unsigned* dst = xh + (((size_t)pbl * 16 + bt) * 2 + half) * 1024;
#pragma unroll
      for (int j = 0; j < 4; ++j) {
        int idx = j * 64 + lane;
        int n = idx >> 4, q4 = idx & 15;
        uint4 v = *(const uint4*)&hb[pbl][n * HP2 + half * 128 + q4 * 8];
        const unsigned* vp = (const unsigned*)&v;
#pragma unroll
        for (int k2 = 0; k2 < 4; ++k2)
          __hip_atomic_store(dst + idx * 4 + k2, vp[k2], __ATOMIC_RELAXED,
                             __HIP_MEMORY_SCOPE_AGENT);
      }
      if (lane == 0)
        __hip_atomic_store(&flags[flo], s - 1, __ATOMIC_RELEASE,
                           __HIP_MEMORY_SCOPE_AGENT);
    }

#pragma unroll
    for (int ktl = 0; ktl < 4; ++ktl) {  // own-half MFMA (overlaps flag latency)
      int kt = half * 4 + ktl;
      uint4 bf = *(const uint4*)&hb[pbl][n16 * HP2 + kt * 32 + quad * 8];
#pragma unroll
      for (int im = 0; im < 2; ++im)
        acc[im] = __builtin_amdgcn_mfma_f32_16x16x32_f16(as_f16x8(areg[im][kt]),
                                                         as_f16x8(bf), acc[im], 0, 0, 0);
    }

    if (w == 0 && tl > 0) {
      while (__hip_atomic_load(&flags[fle], __ATOMIC_RELAXED,
                               __HIP_MEMORY_SCOPE_AGENT) < s - 1)
        __builtin_amdgcn_s_sleep(2);
      (void)__hip_atomic_load(&flags[fle], __ATOMIC_ACQUIRE, __HIP_MEMORY_SCOPE_AGENT);
      const unsigned* src = xh + (((size_t)pbl * 16 + bt) * 2 + phalf) * 1024;
#pragma unroll
      for (int j = 0; j < 4; ++j) {
        int idx = j * 64 + lane;
        int n = idx >> 4, q4 = idx & 15;
        unsigned vv[4];
#pragma unroll
        for (int k2 = 0; k2 < 4; ++k2)
          vv[k2] = __hip_atomic_load(src + idx * 4 + k2, __ATOMIC_RELAXED,
                                     __HIP_MEMORY_SCOPE_AGENT);
        *(uint4*)&hb[pbl][n * HP2 + phalf * 128 + q4 * 8] = *(const uint4*)vv;
      }
    }
    wg_barrier();  // B1: peer h(s-1) in LDS

    // ---- phase 2: peer-half MFMA + fused final linear + gates
#pragma unroll
    for (int ktl = 0; ktl < 4; ++ktl) {
      int kt = phalf * 4 + ktl;
      uint4 bf = *(const uint4*)&hb[pbl][n16 * HP2 + kt * 32 + quad * 8];
#pragma unroll
      for (int im = 0; im < 2; ++im)
        acc[im] = __builtin_amdgcn_mfma_f32_16x16x32_f16(as_f16x8(areg[im][kt]),
                                                         as_f16x8(bf), acc[im], 0, 0, 0);
    }

    if (half == 0 && w == 1 && tl > 0) {  // out(s-1) = tanh(Wl.h(s-1)+bl)
      int n = lane >> 2, seg = lane & 3;
      const unsigned* hrow = (const unsigned*)&hb[pbl][n * HP2];
      float sd = 0.f;
#pragma unroll
      for (int p2 = 0; p2 < 32; ++p2)
        sd = fdot2(hrow[seg * 32 + p2], wls[seg * 32 + p2], sd);
      sd += __shfl_xor(sd, 1); sd += __shfl_xor(sd, 2);
      if (seg == 0) out[(size_t)(b0 + n) * S + (s - 1)] = ftanh_(sd + bl0);
    }

#pragma unroll
    for (int im = 0; im < 2; ++im) {
      float gi = fsig(acc[im][0]);
      float gf = fsig(acc[im][1]);
      float gg = ftanh_(acc[im][2]);
      float go = fsig(acc[im][3]);
      float cn = gf * cst[im] + gi * gg;
      cst[im] = cn;
      hb[pw][n16 * HP2 + (gm0 + im) * 4 + quad] = __float2half_rn(go * ftanh_(cn));
    }
    wg_barrier();  // B2: h(s) own-half complete
  }

  // ---- tail: exchange h(sl), final output, state carry
  {
    const int sl = t0 + Sc - 1, pl = sl & 1;
    if (w == 0) {
      unsigned* dst = xh + (((size_t)pl * 16 + bt) * 2 + half) * 1024;
#pragma unroll
      for (int j = 0; j < 4; ++j) {
        int idx = j * 64 + lane;
        int n = idx >> 4, q4 = idx & 15;
        uint4 v = *(const uint4*)&hb[pl][n * HP2 + half * 128 + q4 * 8];
        const unsigned* vp = (const unsigned*)&v;
#pragma unroll
        for (int k2 = 0; k2 < 4; ++k2)
          __hip_atomic_store(dst + idx * 4 + k2, vp[k2], __ATOMIC_RELAXED,
                             __HIP_MEMORY_SCOPE_AGENT);
      }
      if (lane == 0)
        __hip_atomic_store(&flags[flo], sl, __ATOMIC_RELEASE, __HIP_MEMORY_SCOPE_AGENT);
      if (half == 0) {
        while (__hip_atomic_load(&flags[fle], __ATOMIC_RELAXED,
                                 __HIP_MEMORY_SCOPE_AGENT) < sl)
          __builtin_amdgcn_s_sleep(2);
        (void)__hip_atomic_load(&flags[fle], __ATOMIC_ACQUIRE, __HIP_MEMORY_SCOPE_AGENT);
        const unsigned* src = xh + (((size_t)pl * 16 + bt) * 2 + phalf) * 1024;
#pragma unroll
        for (int j = 0; j < 4; ++j) {
          int idx = j * 64 + lane;
          int n = idx >> 4, q4 = idx & 15;
          unsigned vv[4];
#pragma unroll
          for (int k2 = 0; k2 < 4; ++k2)
            vv[k2] = __hip_atomic_load(src + idx * 4 + k2, __ATOMIC_RELAXED,
                                       __HIP_MEMORY_SCOPE_AGENT);
          *(uint4*)&hb[pl][n * HP2 + phalf * 128 + q4 * 8] = *(const uint4*)vv;
        }
      }
    }
    wg_barrier();
    if (half == 0 && w == 1) {
      int n = lane >> 2, seg = lane & 3;
      const unsigned* hrow = (const unsigned*)&hb[pl][n * HP2];
      float sd = 0.f;
#pragma unroll
      for (int p2 = 0; p2 < 32; ++p2)
        sd = fdot2(hrow[seg * 32 + p2], wls[seg * 32 + p2], sd);
      sd += __shfl_xor(sd, 1); sd += __shfl_xor(sd, 2);
      if (seg == 0) out[(size_t)(b0 + n) * S + sl] = ftanh_(sd + bl0);
    }
    for (int i = tid; i < 16 * 128; i += 1024) {
      int n = i >> 7, c = i & 127;
      sth[(size_t)(b0 + n) * 256 + half * 128 + c] =
          __half2float(hb[pl][n * HP2 + half * 128 + c]);
    }
#pragma unroll
    for (int im = 0; im < 2; ++im) {
      int ch = (gm0 + im) * 4 + quad;
      stc[(size_t)(b0 + n16) * 256 + ch] = cst[im];
    }
  }
}

extern "C" void kernel_launch(void* const* d_in, const int* in_sizes, int n_in,
                              void* d_out, int out_size, void* d_ws, size_t ws_size,
                              hipStream_t stream) {
  (void)in_sizes; (void)n_in; (void)out_size;
  const float* noise = (const float*)d_in[0];
  const float* Wih0 = (const float*)d_in[1];
  const float* Whh0 = (const float*)d_in[2];
  const float* bih0 = (const float*)d_in[3];
  const float* bhh0 = (const float*)d_in[4];
  const float* Wih1 = (const float*)d_in[5];
  const float* Whh1 = (const float*)d_in[6];
  const float* bih1 = (const float*)d_in[7];
  const float* bhh1 = (const float*)d_in[8];
  const float* Wih2 = (const float*)d_in[9];
  const float* Whh2 = (const float*)d_in[10];
  const float* bih2 = (const float*)d_in[11];
  const float* bhh2 = (const float*)d_in[12];
  const float* Wl = (const float*)d_in[13];
  const float* bl = (const float*)d_in[14];
  float* out = (float*)d_out;

  char* p = (char*)d_ws;
  auto alloc = [&](size_t bytes) {
    char* r = p;
    p += (bytes + 255) & ~(size_t)255;
    return r;
  };
  uint4* wpH0 = (uint4*)alloc((size_t)16 * 2 * 1024);
  uint4* wpH1 = (uint4*)alloc((size_t)32 * 4 * 1024);
  uint4* wpH2 = (uint4*)alloc((size_t)64 * 8 * 1024);
  uint4* wpI0 = (uint4*)alloc((size_t)16 * 1 * 1024);
  uint4* wpI1 = (uint4*)alloc((size_t)32 * 2 * 1024);
  uint4* wpI2 = (uint4*)alloc((size_t)64 * 4 * 1024);
  float* bs0 = (float*)alloc(256 * 4);
  float* bs1 = (float*)alloc(512 * 4);
  float* bs2 = (float*)alloc(1024 * 4);
  unsigned* wlp = (unsigned*)alloc(128 * 4);
  float* sh0 = (float*)alloc((size_t)B * H0 * 4);
  float* sc0 = (float*)alloc((size_t)B * H0 * 4);
  float* sh1 = (float*)alloc((size_t)B * H1 * 4);
  float* sc1 = (float*)alloc((size_t)B * H1 * 4);
  float* sh2 = (float*)alloc((size_t)B * H2 * 4);
  float* sc2 = (float*)alloc((size_t)B * H2 * 4);
  __half* x0 = (__half*)alloc((size_t)B * S * 32 * 2);
  __half* x1 = (__half*)alloc((size_t)B * S * H0 * 2);
  __half* x2 = (__half*)alloc((size_t)B * S * H1 * 2);
  unsigned* xh = (unsigned*)alloc((size_t)2 * 16 * 2 * 1024 * 4);
  int* flags = (int*)alloc(64 * 4);
  size_t fixed = (size_t)(p - (char*)d_ws);
  int Sc = 128;
  while (Sc > 16 && fixed + (size_t)B * Sc * 1024 * 4 > ws_size) Sc >>= 1;
  float* preT = (float*)alloc((size_t)B * Sc * 1024 * 4);

  pack_frag<<<(16 * 2 * 64 + 255) / 256, 256, 0, stream>>>(Whh0, wpH0, 64, 64, 16, 2);
  pack_frag<<<(32 * 4 * 64 + 255) / 256, 256, 0, stream>>>(Whh1, wpH1, 128, 128, 32, 4);
  pack_frag<<<(64 * 8 * 64 + 255) / 256, 256, 0, stream>>>(Whh2, wpH2, 256, 256, 64, 8);
  pack_frag<<<(16 * 1 * 64 + 255) / 256, 256, 0, stream>>>(Wih0, wpI0, 64, 32, 16, 1);
  pack_frag<<<(32 * 2 * 64 + 255) / 256, 256, 0, stream>>>(Wih1, wpI1, 128, 64, 32, 2);
  pack_frag<<<(64 * 4 * 64 + 255) / 256, 256, 0, stream>>>(Wih2, wpI2, 256, 128, 64, 4);
  pack_bias<<<1, 256, 0, stream>>>(bih0, bhh0, bs0, 64);
  pack_bias<<<2, 256, 0, stream>>>(bih1, bhh1, bs1, 128);
  pack_bias<<<4, 256, 0, stream>>>(bih2, bhh2, bs2, 256);
  pack_wl<<<1, 128, 0, stream>>>(Wl, wlp, 128);
  f2h<<<(B * S * 32 / 8 + 255) / 256, 256, 0, stream>>>(noise, x0, B * S * 32 / 8);

  for (int c = 0; c < S / Sc; ++c) {
    int t0 = c * Sc;
    ingemm_mfma<1><<<dim3(16, Sc / 8, 1), 256, 0, stream>>>(x0, wpI0, bs0,
                                                            (f32x4*)preT, 16, Sc, t0);
    scan_s1<64><<<16, 512, 0, stream>>>(wpH0, (const f32x4*)preT, x1, sh0, sc0,
                                        Sc, t0, c == 0);
    ingemm_mfma<2><<<dim3(16, Sc / 8, 2), 256, 0, stream>>>(x1, wpI1, bs1,
                                                            (f32x4*)preT, 32, Sc, t0);
    scan_s1<128><<<16, 512, 0, stream>>>(wpH1, (const f32x4*)preT, x2, sh1, sc1,
                                         Sc, t0, c == 0);
    ingemm_mfma<4><<<dim3(16, Sc / 8, 4), 256, 0, stream>>>(x2, wpI2, bs2,
                                                            (f32x4*)preT, 64, Sc, t0);
    scan2_pair<<<32, 1024, 0, stream>>>(wpH2, (const f32x4*)preT, out, wlp, bl,
                                        sh2, sc2, xh, flags, Sc, t0, c == 0);
  }
}

// Round 7
// 3460.583 us; speedup vs baseline: 1.7917x; 1.7917x over previous
//
#include <hip/hip_runtime.h>
#include <hip/hip_fp16.h>

#define DEVINL __device__ __forceinline__

constexpr int B = 256, S = 512;
constexpr int H0 = 64, H1 = 128, H2 = 256;

typedef _Float16 f16x8 __attribute__((ext_vector_type(8)));
typedef float f32x4 __attribute__((ext_vector_type(4)));
typedef _Float16 h2v __attribute__((ext_vector_type(2)));

DEVINL float fexp2(float x) { return __builtin_amdgcn_exp2f(x); }
DEVINL float frcp(float x) { return __builtin_amdgcn_rcpf(x); }
DEVINL float fsig(float x) { return frcp(1.f + fexp2(-1.44269504088896f * x)); }
DEVINL float ftanh_(float x) { return 1.f - 2.f * frcp(1.f + fexp2(2.88539008177793f * x)); }
DEVINL h2v as_h2(unsigned u) { union { unsigned u; h2v h; } x; x.u = u; return x.h; }
DEVINL float fdot2(unsigned a, unsigned b, float c) {
  return __builtin_amdgcn_fdot2(as_h2(a), as_h2(b), c, false);
}
union FU { uint4 u; f16x8 h; };
DEVINL f16x8 as_f16x8(uint4 u) { FU x; x.u = u; return x.h; }

// Identity that the optimizer can't see through: breaks the remat chain of a
// loaded value so the allocator must keep it register-resident.
DEVINL void pin(uint4& v) {
  asm volatile("" : "+v"(v.x), "+v"(v.y), "+v"(v.z), "+v"(v.w));
}

// LDS-only workgroup barrier: no vmcnt drain, global ops stay in flight.
DEVINL void wg_barrier() {
  asm volatile("s_waitcnt lgkmcnt(0)" ::: "memory");
  __builtin_amdgcn_s_barrier();
  asm volatile("" ::: "memory");
}
// Wave-local drain of outstanding global ops (orders data before flag store).
DEVINL void vm_drain() { asm volatile("s_waitcnt vmcnt(0)" ::: "memory"); }

// Row permutation: r' = mt*16 + quad*4 + reg -> channel = r'>>2, gate = r'&3.
// orig torch row = gate*Hch + channel. One C-frag lane holds one channel's
// (i,f,g,o) quad (C: col=lane&15, row=(lane>>4)*4+reg).

__global__ __launch_bounds__(256) void pack_frag(const float* __restrict__ w,
    uint4* __restrict__ wp, int Hch, int Kdim, int MT, int KT) {
  int o = blockIdx.x * 256 + threadIdx.x;
  if (o >= MT * KT * 64) return;
  int lane = o & 63, fk = o >> 6;
  int kt = fk % KT, mt = fk / KT;
  int rp = mt * 16 + (lane & 15);
  int orig = (rp & 3) * Hch + (rp >> 2);
  int k0 = kt * 32 + (lane >> 4) * 8;
  unsigned r[4];
#pragma unroll
  for (int p = 0; p < 4; ++p) {
    unsigned lo = __half_as_ushort(__float2half_rn(w[(size_t)orig * Kdim + k0 + 2 * p]));
    unsigned hi = __half_as_ushort(__float2half_rn(w[(size_t)orig * Kdim + k0 + 2 * p + 1]));
    r[p] = lo | (hi << 16);
  }
  uint4 v; v.x = r[0]; v.y = r[1]; v.z = r[2]; v.w = r[3];
  wp[o] = v;
}

__global__ __launch_bounds__(256) void pack_bias(const float* __restrict__ bih,
    const float* __restrict__ bhh, float* __restrict__ bs, int Hch) {
  int rp = blockIdx.x * 256 + threadIdx.x;
  if (rp >= 4 * Hch) return;
  int orig = (rp & 3) * Hch + (rp >> 2);
  bs[rp] = bih[orig] + bhh[orig];
}

__global__ void pack_wl(const float* __restrict__ wl, unsigned* __restrict__ wlp, int n) {
  int i = threadIdx.x;
  if (i < n) {
    unsigned lo = __half_as_ushort(__float2half_rn(wl[2 * i]));
    unsigned hi = __half_as_ushort(__float2half_rn(wl[2 * i + 1]));
    wlp[i] = lo | (hi << 16);
  }
}

__global__ __launch_bounds__(256) void f2h(const float* __restrict__ x,
                                           __half* __restrict__ y, int n8) {
  int i = blockIdx.x * 256 + threadIdx.x;
  if (i >= n8) return;
  float4 a = *(const float4*)(x + i * 8);
  float4 b = *(const float4*)(x + i * 8 + 4);
  __half h[8];
  h[0] = __float2half_rn(a.x); h[1] = __float2half_rn(a.y);
  h[2] = __float2half_rn(a.z); h[3] = __float2half_rn(a.w);
  h[4] = __float2half_rn(b.x); h[5] = __float2half_rn(b.y);
  h[6] = __float2half_rn(b.z); h[7] = __float2half_rn(b.w);
  *(uint4*)(y + i * 8) = *(const uint4*)h;
}

// MFMA input GEMM -> preT in C-frag layout.
template <int KT>
__global__ __launch_bounds__(256) __attribute__((amdgpu_waves_per_eu(4, 4)))
void ingemm_mfma(const __half* __restrict__ x,
    const uint4* __restrict__ wp, const float* __restrict__ bs,
    f32x4* __restrict__ preT, int MT, int Sc, int t0) {
  constexpr int K = KT * 32;
  const int tid = threadIdx.x, w = tid >> 6, lane = tid & 63;
  const int n16 = lane & 15, quad = lane >> 4;
  const int bt = blockIdx.x, b0 = bt * 16;
  const int tlb = blockIdx.y * 8;
  const int mb = blockIdx.z * 16;

  uint4 areg[4][KT];
#pragma unroll
  for (int im = 0; im < 4; ++im)
#pragma unroll
    for (int kt = 0; kt < KT; ++kt) {
      areg[im][kt] = wp[((size_t)(mb + w * 4 + im) * KT + kt) * 64 + lane];
      pin(areg[im][kt]);
    }
  f32x4 bini[4];
#pragma unroll
  for (int im = 0; im < 4; ++im)
    bini[im] = *(const f32x4*)(bs + (mb + w * 4 + im) * 16 + quad * 4);

  for (int tt = 0; tt < 8; ++tt) {
    int t = t0 + tlb + tt;
    const __half* xr = x + ((size_t)(b0 + n16) * S + t) * K + quad * 8;
    uint4 bfr[KT];
#pragma unroll
    for (int kt = 0; kt < KT; ++kt) bfr[kt] = *(const uint4*)(xr + kt * 32);
    f32x4 acc[4];
#pragma unroll
    for (int im = 0; im < 4; ++im) acc[im] = bini[im];
#pragma unroll
    for (int kt = 0; kt < KT; ++kt)
#pragma unroll
      for (int im = 0; im < 4; ++im)
        acc[im] = __builtin_amdgcn_mfma_f32_16x16x32_f16(as_f16x8(areg[im][kt]),
                                                         as_f16x8(bfr[kt]), acc[im], 0, 0, 0);
#pragma unroll
    for (int im = 0; im < 4; ++im)
      preT[((size_t)(bt * Sc + tlb + tt) * MT + mb + w * 4 + im) * 64 + lane] = acc[im];
  }
}

// Single-WG weight-stationary scan (layers 0/1). 16 WGs x 16 batch, 512 thr.
template <int H>
__global__ __launch_bounds__(512) __attribute__((amdgpu_waves_per_eu(2, 2)))
void scan_s1(const uint4* __restrict__ wp, const f32x4* __restrict__ preT,
             __half* __restrict__ xout, float* __restrict__ sth,
             float* __restrict__ stc, int Sc, int t0, int first) {
  constexpr int MT = H / 4;
  constexpr int MTW = MT / 8;
  constexpr int KT = H / 32;
  constexpr int HP = H + 8;
  __shared__ __half hbo[2][16 * HP];
  const int tid = threadIdx.x, w = tid >> 6, lane = tid & 63;
  const int n16 = lane & 15, quad = lane >> 4;
  const int bt = blockIdx.x, b0 = bt * 16;

  uint4 areg[MTW][KT];
#pragma unroll
  for (int im = 0; im < MTW; ++im)
#pragma unroll
    for (int kt = 0; kt < KT; ++kt) {
      areg[im][kt] = wp[((size_t)(w * MTW + im) * KT + kt) * 64 + lane];
      pin(areg[im][kt]);
    }

  float cst[MTW];
#pragma unroll
  for (int im = 0; im < MTW; ++im) {
    int ch = (w * MTW + im) * 4 + quad;
    cst[im] = first ? 0.f : stc[(size_t)(b0 + n16) * H + ch];
  }
  {
    int pi = (t0 - 1) & 1;
    for (int i = tid; i < 16 * H; i += 512) {
      int n = i / H, c = i % H;
      hbo[pi][n * HP + c] = first ? __float2half_rn(0.f)
                                  : __float2half_rn(sth[(size_t)(b0 + n) * H + c]);
    }
  }
  __syncthreads();

  f32x4 nxt[MTW];
#pragma unroll
  for (int im = 0; im < MTW; ++im)
    nxt[im] = preT[((size_t)(bt * Sc) * MT + w * MTW + im) * 64 + lane];

  for (int tl = 0; tl < Sc; ++tl) {
    const int s = t0 + tl;
    const int pw = s & 1, pbl = pw ^ 1;
    f32x4 acc[MTW];
#pragma unroll
    for (int im = 0; im < MTW; ++im) acc[im] = nxt[im];
    if (tl + 1 < Sc) {
#pragma unroll
      for (int im = 0; im < MTW; ++im)
        nxt[im] = preT[((size_t)(bt * Sc + tl + 1) * MT + w * MTW + im) * 64 + lane];
    }

#pragma unroll
    for (int kt = 0; kt < KT; ++kt) {
      uint4 bf = *(const uint4*)&hbo[pbl][n16 * HP + kt * 32 + quad * 8];
#pragma unroll
      for (int im = 0; im < MTW; ++im)
        acc[im] = __builtin_amdgcn_mfma_f32_16x16x32_f16(as_f16x8(areg[im][kt]),
                                                         as_f16x8(bf), acc[im], 0, 0, 0);
    }

    if (tl > 0 && tid < 16 * (H / 8)) {  // export h(s-1)
      int n = tid / (H / 8), kq = tid % (H / 8);
      uint4 v = *(const uint4*)&hbo[pbl][n * HP + kq * 8];
      *(uint4*)(xout + ((size_t)(b0 + n) * S + (s - 1)) * H + kq * 8) = v;
    }

#pragma unroll
    for (int im = 0; im < MTW; ++im) {
      float gi = fsig(acc[im][0]);
      float gf = fsig(acc[im][1]);
      float gg = ftanh_(acc[im][2]);
      float go = fsig(acc[im][3]);
      float cn = gf * cst[im] + gi * gg;
      cst[im] = cn;
      hbo[pw][n16 * HP + (w * MTW + im) * 4 + quad] = __float2half_rn(go * ftanh_(cn));
    }
    wg_barrier();
  }

  {
    const int sl = t0 + Sc - 1, pl = sl & 1;
    if (tid < 16 * (H / 8)) {
      int n = tid / (H / 8), kq = tid % (H / 8);
      uint4 v = *(const uint4*)&hbo[pl][n * HP + kq * 8];
      *(uint4*)(xout + ((size_t)(b0 + n) * S + sl) * H + kq * 8) = v;
    }
    for (int i = tid; i < 16 * H; i += 512) {
      int n = i / H, c = i % H;
      sth[(size_t)(b0 + n) * H + c] = __half2float(hbo[pl][n * HP + c]);
    }
#pragma unroll
    for (int im = 0; im < MTW; ++im) {
      int ch = (w * MTW + im) * 4 + quad;
      stc[(size_t)(b0 + n16) * H + ch] = cst[im];
    }
  }
}

// Layer-2 scan: 32 WGs (16 batch-group pairs) x 1024 thr (16 waves, 4/EU).
// Each WG owns half the m-dim. Weights: aown/apeer, statically indexed +
// pin()ed -> genuinely register-resident (64 VGPRs). Cross-WG h exchange is
// acquire/release-FREE: relaxed agent-scope 8B atomics (bypass non-coherent
// L2s, meet at LLC) + wave-local vmcnt drain before a relaxed flag store.
// Wave 0 alone runs the protocol; two LDS-only barriers per step.
__global__ __launch_bounds__(1024) __attribute__((amdgpu_waves_per_eu(4, 4)))
void scan2_pair(const uint4* __restrict__ wp, const f32x4* __restrict__ preT,
                float* __restrict__ out, const unsigned* __restrict__ wlp,
                const float* __restrict__ blp, float* __restrict__ sth,
                float* __restrict__ stc, unsigned long long* __restrict__ xh,
                int* __restrict__ flags, int Sc, int t0, int first) {
  constexpr int HP2 = 264;  // padded row in halves (256+8)
  __shared__ __half hb[2][16 * HP2];
  __shared__ unsigned wls[128];

  const int tid = threadIdx.x, w = tid >> 6, lane = tid & 63;
  const int n16 = lane & 15, quad = lane >> 4;
  const int bt = blockIdx.x & 15, half = blockIdx.x >> 4;
  const int phalf = 1 - half;
  const int b0 = bt * 16;
  const int gm0 = half * 32 + w * 2;  // this wave's 2 m-tiles (of 64)
  const int flo = bt * 2 + half, fle = bt * 2 + phalf;

  // statically-indexed weight arrays (dynamic indexing forces demotion!)
  uint4 aown[2][4], apeer[2][4];
#pragma unroll
  for (int im = 0; im < 2; ++im)
#pragma unroll
    for (int ktl = 0; ktl < 4; ++ktl) {
      aown[im][ktl] = wp[((size_t)(gm0 + im) * 8 + half * 4 + ktl) * 64 + lane];
      pin(aown[im][ktl]);
      apeer[im][ktl] = wp[((size_t)(gm0 + im) * 8 + phalf * 4 + ktl) * 64 + lane];
      pin(apeer[im][ktl]);
    }

  for (int i = tid; i < 128; i += 1024) wls[i] = wlp[i];

  float cst[2];
#pragma unroll
  for (int im = 0; im < 2; ++im) {
    int ch = (gm0 + im) * 4 + quad;
    cst[im] = first ? 0.f : stc[(size_t)(b0 + n16) * 256 + ch];
  }
  {
    int pi = (t0 - 1) & 1;
    for (int i = tid; i < 16 * 256; i += 1024) {
      int n = i >> 8, c = i & 255;
      hb[pi][n * HP2 + c] = first ? __float2half_rn(0.f)
                                  : __float2half_rn(sth[(size_t)(b0 + n) * 256 + c]);
    }
  }
  __syncthreads();

  const float bl0 = blp[0];

  f32x4 nxt[2];
#pragma unroll
  for (int im = 0; im < 2; ++im)
    nxt[im] = preT[((size_t)(bt * Sc) * 64 + gm0 + im) * 64 + lane];

  for (int tl = 0; tl < Sc; ++tl) {
    const int s = t0 + tl;
    const int pw = s & 1, pbl = pw ^ 1;
    f32x4 acc[2];
    acc[0] = nxt[0]; acc[1] = nxt[1];
    if (tl + 1 < Sc) {
#pragma unroll
      for (int im = 0; im < 2; ++im)
        nxt[im] = preT[((size_t)(bt * Sc + tl + 1) * 64 + gm0 + im) * 64 + lane];
    }

    // ---- phase 1: wave0 exports h(s-1) own half (relaxed atomics + flag)
    if (w == 0 && tl > 0) {
      unsigned long long* dst = xh + (((size_t)pbl * 16 + bt) * 2 + half) * 512;
#pragma unroll
      for (int j = 0; j < 4; ++j) {
        int idx = j * 64 + lane;
        int n = idx >> 4, q4 = idx & 15;
        uint4 v = *(const uint4*)&hb[pbl][n * HP2 + half * 128 + q4 * 8];
        unsigned long long lo = ((unsigned long long)v.y << 32) | v.x;
        unsigned long long hi = ((unsigned long long)v.w << 32) | v.z;
        __hip_atomic_store(dst + idx * 2, lo, __ATOMIC_RELAXED, __HIP_MEMORY_SCOPE_AGENT);
        __hip_atomic_store(dst + idx * 2 + 1, hi, __ATOMIC_RELAXED,
                           __HIP_MEMORY_SCOPE_AGENT);
      }
      vm_drain();  // data at LLC before flag
      if (lane == 0)
        __hip_atomic_store(&flags[flo], s - 1, __ATOMIC_RELAXED, __HIP_MEMORY_SCOPE_AGENT);
    }

#pragma unroll
    for (int ktl = 0; ktl < 4; ++ktl) {  // own-half MFMA (overlaps exchange)
      uint4 bf = *(const uint4*)&hb[pbl][n16 * HP2 + (half * 4 + ktl) * 32 + quad * 8];
#pragma unroll
      for (int im = 0; im < 2; ++im)
        acc[im] = __builtin_amdgcn_mfma_f32_16x16x32_f16(as_f16x8(aown[im][ktl]),
                                                         as_f16x8(bf), acc[im], 0, 0, 0);
    }

    if (w == 0 && tl > 0) {  // poll (relaxed) + import peer half
      while (__hip_atomic_load(&flags[fle], __ATOMIC_RELAXED,
                               __HIP_MEMORY_SCOPE_AGENT) < s - 1)
        __builtin_amdgcn_s_sleep(1);
      const unsigned long long* src = xh + (((size_t)pbl * 16 + bt) * 2 + phalf) * 512;
#pragma unroll
      for (int j = 0; j < 4; ++j) {
        int idx = j * 64 + lane;
        int n = idx >> 4, q4 = idx & 15;
        unsigned long long lo = __hip_atomic_load(src + idx * 2, __ATOMIC_RELAXED,
                                                  __HIP_MEMORY_SCOPE_AGENT);
        unsigned long long hi = __hip_atomic_load(src + idx * 2 + 1, __ATOMIC_RELAXED,
                                                  __HIP_MEMORY_SCOPE_AGENT);
        uint4 v;
        v.x = (unsigned)lo; v.y = (unsigned)(lo >> 32);
        v.z = (unsigned)hi; v.w = (unsigned)(hi >> 32);
        *(uint4*)&hb[pbl][n * HP2 + phalf * 128 + q4 * 8] = v;
      }
    }
    wg_barrier();  // B1: peer h(s-1) in LDS

    // ---- phase 2: peer-half MFMA + fused final linear + gates
#pragma unroll
    for (int ktl = 0; ktl < 4; ++ktl) {
      uint4 bf = *(const uint4*)&hb[pbl][n16 * HP2 + (phalf * 4 + ktl) * 32 + quad * 8];
#pragma unroll
      for (int im = 0; im < 2; ++im)
        acc[im] = __builtin_amdgcn_mfma_f32_16x16x32_f16(as_f16x8(apeer[im][ktl]),
                                                         as_f16x8(bf), acc[im], 0, 0, 0);
    }

    if (half == 0 && w == 1 && tl > 0) {  // out(s-1) = tanh(Wl.h(s-1)+bl)
      int n = lane >> 2, seg = lane & 3;
      const unsigned* hrow = (const unsigned*)&hb[pbl][n * HP2];
      float sd = 0.f;
#pragma unroll
      for (int p2 = 0; p2 < 32; ++p2)
        sd = fdot2(hrow[seg * 32 + p2], wls[seg * 32 + p2], sd);
      sd += __shfl_xor(sd, 1); sd += __shfl_xor(sd, 2);
      if (seg == 0) out[(size_t)(b0 + n) * S + (s - 1)] = ftanh_(sd + bl0);
    }

#pragma unroll
    for (int im = 0; im < 2; ++im) {
      float gi = fsig(acc[im][0]);
      float gf = fsig(acc[im][1]);
      float gg = ftanh_(acc[im][2]);
      float go = fsig(acc[im][3]);
      float cn = gf * cst[im] + gi * gg;
      cst[im] = cn;
      hb[pw][n16 * HP2 + (gm0 + im) * 4 + quad] = __float2half_rn(go * ftanh_(cn));
    }
    wg_barrier();  // B2: h(s) own-half complete
  }

  // ---- tail: exchange h(sl), final output, state carry
  {
    const int sl = t0 + Sc - 1, pl = sl & 1;
    if (w == 0) {
      unsigned long long* dst = xh + (((size_t)pl * 16 + bt) * 2 + half) * 512;
#pragma unroll
      for (int j = 0; j < 4; ++j) {
        int idx = j * 64 + lane;
        int n = idx >> 4, q4 = idx & 15;
        uint4 v = *(const uint4*)&hb[pl][n * HP2 + half * 128 + q4 * 8];
        unsigned long long lo = ((unsigned long long)v.y << 32) | v.x;
        unsigned long long hi = ((unsigned long long)v.w << 32) | v.z;
        __hip_atomic_store(dst + idx * 2, lo, __ATOMIC_RELAXED, __HIP_MEMORY_SCOPE_AGENT);
        __hip_atomic_store(dst + idx * 2 + 1, hi, __ATOMIC_RELAXED,
                           __HIP_MEMORY_SCOPE_AGENT);
      }
      vm_drain();
      if (lane == 0)
        __hip_atomic_store(&flags[flo], sl, __ATOMIC_RELAXED, __HIP_MEMORY_SCOPE_AGENT);
      if (half == 0) {
        while (__hip_atomic_load(&flags[fle], __ATOMIC_RELAXED,
                                 __HIP_MEMORY_SCOPE_AGENT) < sl)
          __builtin_amdgcn_s_sleep(1);
        const unsigned long long* src = xh + (((size_t)pl * 16 + bt) * 2 + phalf) * 512;
#pragma unroll
        for (int j = 0; j < 4; ++j) {
          int idx = j * 64 + lane;
          int n = idx >> 4, q4 = idx & 15;
          unsigned long long lo = __hip_atomic_load(src + idx * 2, __ATOMIC_RELAXED,
                                                    __HIP_MEMORY_SCOPE_AGENT);
          unsigned long long hi = __hip_atomic_load(src + idx * 2 + 1, __ATOMIC_RELAXED,
                                                    __HIP_MEMORY_SCOPE_AGENT);
          uint4 v;
          v.x = (unsigned)lo; v.y = (unsigned)(lo >> 32);
          v.z = (unsigned)hi; v.w = (unsigned)(hi >> 32);
          *(uint4*)&hb[pl][n * HP2 + phalf * 128 + q4 * 8] = v;
        }
      }
    }
    wg_barrier();
    if (half == 0 && w == 1) {
      int n = lane >> 2, seg = lane & 3;
      const unsigned* hrow = (const unsigned*)&hb[pl][n * HP2];
      float sd = 0.f;
#pragma unroll
      for (int p2 = 0; p2 < 32; ++p2)
        sd = fdot2(hrow[seg * 32 + p2], wls[seg * 32 + p2], sd);
      sd += __shfl_xor(sd, 1); sd += __shfl_xor(sd, 2);
      if (seg == 0) out[(size_t)(b0 + n) * S + sl] = ftanh_(sd + bl0);
    }
    for (int i = tid; i < 16 * 128; i += 1024) {
      int n = i >> 7, c = i & 127;
      sth[(size_t)(b0 + n) * 256 + half * 128 + c] =
          __half2float(hb[pl][n * HP2 + half * 128 + c]);
    }
#pragma unroll
    for (int im = 0; im < 2; ++im) {
      int ch = (gm0 + im) * 4 + quad;
      stc[(size_t)(b0 + n16) * 256 + ch] = cst[im];
    }
  }
}

extern "C" void kernel_launch(void* const* d_in, const int* in_sizes, int n_in,
                              void* d_out, int out_size, void* d_ws, size_t ws_size,
                              hipStream_t stream) {
  (void)in_sizes; (void)n_in; (void)out_size;
  const float* noise = (const float*)d_in[0];
  const float* Wih0 = (const float*)d_in[1];
  const float* Whh0 = (const float*)d_in[2];
  const float* bih0 = (const float*)d_in[3];
  const float* bhh0 = (const float*)d_in[4];
  const float* Wih1 = (const float*)d_in[5];
  const float* Whh1 = (const float*)d_in[6];
  const float* bih1 = (const float*)d_in[7];
  const float* bhh1 = (const float*)d_in[8];
  const float* Wih2 = (const float*)d_in[9];
  const float* Whh2 = (const float*)d_in[10];
  const float* bih2 = (const float*)d_in[11];
  const float* bhh2 = (const float*)d_in[12];
  const float* Wl = (const float*)d_in[13];
  const float* bl = (const float*)d_in[14];
  float* out = (float*)d_out;

  char* p = (char*)d_ws;
  auto alloc = [&](size_t bytes) {
    char* r = p;
    p += (bytes + 255) & ~(size_t)255;
    return r;
  };
  uint4* wpH0 = (uint4*)alloc((size_t)16 * 2 * 1024);
  uint4* wpH1 = (uint4*)alloc((size_t)32 * 4 * 1024);
  uint4* wpH2 = (uint4*)alloc((size_t)64 * 8 * 1024);
  uint4* wpI0 = (uint4*)alloc((size_t)16 * 1 * 1024);
  uint4* wpI1 = (uint4*)alloc((size_t)32 * 2 * 1024);
  uint4* wpI2 = (uint4*)alloc((size_t)64 * 4 * 1024);
  float* bs0 = (float*)alloc(256 * 4);
  float* bs1 = (float*)alloc(512 * 4);
  float* bs2 = (float*)alloc(1024 * 4);
  unsigned* wlp = (unsigned*)alloc(128 * 4);
  float* sh0 = (float*)alloc((size_t)B * H0 * 4);
  float* sc0 = (float*)alloc((size_t)B * H0 * 4);
  float* sh1 = (float*)alloc((size_t)B * H1 * 4);
  float* sc1 = (float*)alloc((size_t)B * H1 * 4);
  float* sh2 = (float*)alloc((size_t)B * H2 * 4);
  float* sc2 = (float*)alloc((size_t)B * H2 * 4);
  __half* x0 = (__half*)alloc((size_t)B * S * 32 * 2);
  __half* x1 = (__half*)alloc((size_t)B * S * H0 * 2);
  __half* x2 = (__half*)alloc((size_t)B * S * H1 * 2);
  unsigned long long* xh = (unsigned long long*)alloc((size_t)2 * 16 * 2 * 512 * 8);
  int* flags = (int*)alloc(64 * 4);
  size_t fixed = (size_t)(p - (char*)d_ws);
  int Sc = 128;
  while (Sc > 16 && fixed + (size_t)B * Sc * 1024 * 4 > ws_size) Sc >>= 1;
  float* preT = (float*)alloc((size_t)B * Sc * 1024 * 4);

  pack_frag<<<(16 * 2 * 64 + 255) / 256, 256, 0, stream>>>(Whh0, wpH0, 64, 64, 16, 2);
  pack_frag<<<(32 * 4 * 64 + 255) / 256, 256, 0, stream>>>(Whh1, wpH1, 128, 128, 32, 4);
  pack_frag<<<(64 * 8 * 64 + 255) / 256, 256, 0, stream>>>(Whh2, wpH2, 256, 256, 64, 8);
  pack_frag<<<(16 * 1 * 64 + 255) / 256, 256, 0, stream>>>(Wih0, wpI0, 64, 32, 16, 1);
  pack_frag<<<(32 * 2 * 64 + 255) / 256, 256, 0, stream>>>(Wih1, wpI1, 128, 64, 32, 2);
  pack_frag<<<(64 * 4 * 64 + 255) / 256, 256, 0, stream>>>(Wih2, wpI2, 256, 128, 64, 4);
  pack_bias<<<1, 256, 0, stream>>>(bih0, bhh0, bs0, 64);
  pack_bias<<<2, 256, 0, stream>>>(bih1, bhh1, bs1, 128);
  pack_bias<<<4, 256, 0, stream>>>(bih2, bhh2, bs2, 256);
  pack_wl<<<1, 128, 0, stream>>>(Wl, wlp, 128);
  f2h<<<(B * S * 32 / 8 + 255) / 256, 256, 0, stream>>>(noise, x0, B * S * 32 / 8);

  for (int c = 0; c < S / Sc; ++c) {
    int t0 = c * Sc;
    ingemm_mfma<1><<<dim3(16, Sc / 8, 1), 256, 0, stream>>>(x0, wpI0, bs0,
                                                            (f32x4*)preT, 16, Sc, t0);
    scan_s1<64><<<16, 512, 0, stream>>>(wpH0, (const f32x4*)preT, x1, sh0, sc0,
                                        Sc, t0, c == 0);
    ingemm_mfma<2><<<dim3(16, Sc / 8, 2), 256, 0, stream>>>(x1, wpI1, bs1,
                                                            (f32x4*)preT, 32, Sc, t0);
    scan_s1<128><<<16, 512, 0, stream>>>(wpH1, (const f32x4*)preT, x2, sh1, sc1,
                                         Sc, t0, c == 0);
    ingemm_mfma<4><<<dim3(16, Sc / 8, 4), 256, 0, stream>>>(x2, wpI2, bs2,
                                                            (f32x4*)preT, 64, Sc, t0);
    scan2_pair<<<32, 1024, 0, stream>>>(wpH2, (const f32x4*)preT, out, wlp, bl,
                                        sh2, sc2, xh, flags, Sc, t0, c == 0);
  }
}